// Round 6
// baseline (651.203 us; speedup 1.0000x reference)
//
#include <hip/hip_runtime.h>
#include <math.h>

#define NDIM 4096
#define MDIM 4096
#define DDIM 1024
#define NITER 20   // contraction = fi^2 = 0.25/iter; log-err 4*0.25^20 ~ 4e-12 << fp32 noise; ref's 200 = same fixed point

typedef float f4  __attribute__((ext_vector_type(4)));
typedef short s8v __attribute__((ext_vector_type(8)));          // 8 bf16 bit-patterns (4 VGPRs) - MFMA A/B frag
typedef unsigned short us4 __attribute__((ext_vector_type(4)));
typedef unsigned short us8 __attribute__((ext_vector_type(8)));

static __device__ __forceinline__ unsigned short f2bf(float f) {
    unsigned int u = __float_as_uint(f);
    unsigned int r = (u + 0x7FFFu + ((u >> 16) & 1u)) >> 16;   // RNE
    return (unsigned short)r;
}
static __device__ __forceinline__ float bf2f(unsigned int bits16) {
    return __uint_as_float(bits16 << 16);
}

// ---------------------------------------------------------------- v = 1/m
__global__ __launch_bounds__(256) void k_init_v(float* __restrict__ v) {
    int i = blockIdx.x * 256 + threadIdx.x;
    if (i < MDIM) v[i] = 1.0f / (float)MDIM;
}

// ---------------------------------------------------------------- norms + bf16 convert (1 row/wave, rows 0..8191)
__global__ __launch_bounds__(256) void k_prep(const float* __restrict__ x, const float* __restrict__ y,
                                              float* __restrict__ inx, float* __restrict__ iny,
                                              unsigned short* __restrict__ xb, unsigned short* __restrict__ yb) {
    int row  = blockIdx.x * 4 + (threadIdx.x >> 6);
    int lane = threadIdx.x & 63;
    const float* src; float* dstn; unsigned short* dstb; int r;
    if (row < NDIM) { src = x; dstn = inx; dstb = xb; r = row; }
    else            { src = y; dstn = iny; dstb = yb; r = row - NDIM; }
    const f4* p = (const f4*)(src + (size_t)r * DDIM);
    float s = 0.0f;
    #pragma unroll
    for (int c = 0; c < 4; ++c) {
        f4 f = p[c * 64 + lane];
        s += f[0]*f[0] + f[1]*f[1] + f[2]*f[2] + f[3]*f[3];
        us4 h;
        #pragma unroll
        for (int e = 0; e < 4; ++e) h[e] = f2bf(f[e]);
        *(us4*)&dstb[(size_t)r * DDIM + (c * 64 + lane) * 4] = h;
    }
    #pragma unroll
    for (int off = 32; off; off >>= 1) s += __shfl_down(s, off, 64);
    if (lane == 0) dstn[r] = 1.0f / sqrtf(s);
}

// ---------------------------------------------------------------- transpose(+exp) convert: dst[j][i] = bf16(f(src[i][j]))
template<int SRCW, int DSTW, int DOEXP>
__global__ __launch_bounds__(256) void k_trans_cvt(const float* __restrict__ src, unsigned short* __restrict__ dst) {
    __shared__ __align__(16) unsigned short t[64][72];
    const int i0 = blockIdx.y * 64, j0 = blockIdx.x * 64;
    const int r  = threadIdx.x >> 2;          // 0..63
    const int c0 = (threadIdx.x & 3) * 16;    // 0,16,32,48
    #pragma unroll
    for (int q = 0; q < 4; ++q) {
        f4 f = *(const f4*)&src[(size_t)(i0 + r) * SRCW + j0 + c0 + q * 4];
        #pragma unroll
        for (int e = 0; e < 4; ++e) {
            float val = DOEXP ? expf(f[e]) : f[e];
            t[c0 + q * 4 + e][r] = f2bf(val);
        }
    }
    __syncthreads();
    const int jj  = threadIdx.x >> 2;
    const int ii0 = (threadIdx.x & 3) * 16;
    #pragma unroll
    for (int h = 0; h < 2; ++h)
        *(us8*)&dst[(size_t)(j0 + jj) * DSTW + i0 + ii0 + h * 8] = *(const us8*)&t[jj][ii0 + h * 8];
}

// ---------------------------------------------------------------- bf16 NT MFMA GEMM: C[i][j] = dot(Arow_i, Brow_j) (*scA_i*scB_j)
// 128x128 tile, 4 waves (2x2), per wave 64x64 via 4x4 mfma_f32_16x16x32_bf16, BK=64, padded LDS (144B stride)
template<int KDIM, int CSTRIDE, int SCALE>
__global__ __launch_bounds__(256) void k_gemm_nt(const unsigned short* __restrict__ Amat,
                                                 const unsigned short* __restrict__ Bmat,
                                                 const float* __restrict__ scA, const float* __restrict__ scB,
                                                 float* __restrict__ C) {
    __shared__ __align__(16) short xs[128 * 72];
    __shared__ __align__(16) short ys[128 * 72];
    const int tid  = threadIdx.x;
    const int wave = tid >> 6, lane = tid & 63;
    const int wr = wave >> 1, wc = wave & 1;          // 2x2 wave grid
    const int i0 = blockIdx.y * 128;
    const int j0 = blockIdx.x * 128;
    f4 acc[4][4];
    #pragma unroll
    for (int a = 0; a < 4; ++a)
        #pragma unroll
        for (int b = 0; b < 4; ++b) acc[a][b] = (f4)0.0f;

    const int srow = tid >> 3;          // 0..31
    const int scol = (tid & 7) * 8;     // bf16 col 0..56
    const int frow = lane & 15;         // A-row / B-col within 16-tile
    const int fkg  = lane >> 4;         // k-group 0..3 (8 bf16 each)

    for (int k0 = 0; k0 < KDIM; k0 += 64) {
        __syncthreads();   // previous iter's reads done before overwrite
        #pragma unroll
        for (int q = 0; q < 4; ++q) {
            int r = q * 32 + srow;
            *(us8*)&xs[r * 72 + scol] = *(const us8*)&Amat[(size_t)(i0 + r) * KDIM + k0 + scol];
            *(us8*)&ys[r * 72 + scol] = *(const us8*)&Bmat[(size_t)(j0 + r) * KDIM + k0 + scol];
        }
        __syncthreads();
        #pragma unroll
        for (int ks = 0; ks < 2; ++ks) {
            s8v af[4], bfr[4];
            #pragma unroll
            for (int t = 0; t < 4; ++t)
                af[t]  = *(const s8v*)&xs[(wr * 64 + t * 16 + frow) * 72 + ks * 32 + fkg * 8];
            #pragma unroll
            for (int t = 0; t < 4; ++t)
                bfr[t] = *(const s8v*)&ys[(wc * 64 + t * 16 + frow) * 72 + ks * 32 + fkg * 8];
            #pragma unroll
            for (int mr = 0; mr < 4; ++mr)
                #pragma unroll
                for (int nc = 0; nc < 4; ++nc)
                    acc[mr][nc] = __builtin_amdgcn_mfma_f32_16x16x32_bf16(af[mr], bfr[nc], acc[mr][nc], 0, 0, 0);
        }
    }
    // C/D layout (HW-verified m89): col = lane&15, row = (lane>>4)*4 + reg
    const int lrow = (lane >> 4) * 4;
    const int lcol = lane & 15;
    #pragma unroll
    for (int nc = 0; nc < 4; ++nc) {
        int jb = j0 + wc * 64 + nc * 16 + lcol;
        float sb = SCALE ? scB[jb] : 1.0f;
        #pragma unroll
        for (int mr = 0; mr < 4; ++mr) {
            #pragma unroll
            for (int r = 0; r < 4; ++r) {
                int ib = i0 + wr * 64 + mr * 16 + lrow + r;
                float val = acc[mr][nc][r];
                if (SCALE) val *= scA[ib] * sb;
                C[(size_t)ib * CSTRIDE + jb] = val;
            }
        }
    }
}

// ---------------------------------------------------------------- u-step: u = sqrt((1/4096) / (exp(A) @ v)), fp32 A read
__global__ __launch_bounds__(256) void k_ustep(const float* __restrict__ Amat,
                                               const float* __restrict__ vin, float* __restrict__ uout) {
    const int row  = blockIdx.x * 4 + (threadIdx.x >> 6);
    const int lane = threadIdx.x & 63;
    const float* Arow = Amat + (size_t)row * MDIM;
    double acc = 0.0;
    #pragma unroll
    for (int c = 0; c < 16; ++c) {
        int j = (c * 64 + lane) * 4;
        f4 a = *(const f4*)&Arow[j];
        f4 v = *(const f4*)&vin[j];
        acc += (double)(expf(a[0])*v[0] + expf(a[1])*v[1] + expf(a[2])*v[2] + expf(a[3])*v[3]);
    }
    #pragma unroll
    for (int off = 32; off; off >>= 1) acc += __shfl_xor(acc, off, 64);
    if (lane == 0) uout[row] = (float)sqrt((1.0 / 4096.0) / acc);
}

// ---------------------------------------------------------------- v-step: v = sqrt((1/4096) / (KbT @ u)), bf16 KbT read
__global__ __launch_bounds__(256) void k_vstep(const unsigned short* __restrict__ KbT,
                                               const float* __restrict__ uin, float* __restrict__ vout) {
    const int row  = blockIdx.x * 4 + (threadIdx.x >> 6);
    const int lane = threadIdx.x & 63;
    const unsigned short* Krow = KbT + (size_t)row * NDIM;
    float acc = 0.0f;
    #pragma unroll
    for (int c = 0; c < 8; ++c) {
        int j = (c * 64 + lane) * 8;
        us8 kq = *(const us8*)&Krow[j];
        f4 ua = *(const f4*)&uin[j];
        f4 ub = *(const f4*)&uin[j + 4];
        acc += bf2f(kq[0])*ua[0] + bf2f(kq[1])*ua[1] + bf2f(kq[2])*ua[2] + bf2f(kq[3])*ua[3]
             + bf2f(kq[4])*ub[0] + bf2f(kq[5])*ub[1] + bf2f(kq[6])*ub[2] + bf2f(kq[7])*ub[3];
    }
    #pragma unroll
    for (int off = 32; off; off >>= 1) acc += __shfl_xor(acc, off, 64);
    if (lane == 0) vout[row] = sqrtf((1.0f / 4096.0f) / acc);
}

// ---------------------------------------------------------------- T = A*u_i*exp(A)*v_j in place + TbT = bf16(T^T)
__global__ __launch_bounds__(256) void k_epiT2(float* __restrict__ Am,
                                               const float* __restrict__ u, const float* __restrict__ v,
                                               unsigned short* __restrict__ TbT) {
    __shared__ __align__(16) unsigned short t[64][72];
    const int i0 = blockIdx.y * 64, j0 = blockIdx.x * 64;
    const int r  = threadIdx.x >> 2;
    const int c0 = (threadIdx.x & 3) * 16;
    const float ui = u[i0 + r];
    #pragma unroll
    for (int q = 0; q < 4; ++q) {
        f4 a  = *(const f4*)&Am[(size_t)(i0 + r) * MDIM + j0 + c0 + q * 4];
        f4 vv = *(const f4*)&v[j0 + c0 + q * 4];
        f4 tt;
        #pragma unroll
        for (int e = 0; e < 4; ++e) tt[e] = a[e] * ui * expf(a[e]) * vv[e];
        *(f4*)&Am[(size_t)(i0 + r) * MDIM + j0 + c0 + q * 4] = tt;
        #pragma unroll
        for (int e = 0; e < 4; ++e) t[c0 + q * 4 + e][r] = f2bf(tt[e]);
    }
    __syncthreads();
    const int jj  = threadIdx.x >> 2;
    const int ii0 = (threadIdx.x & 3) * 16;
    #pragma unroll
    for (int h = 0; h < 2; ++h)
        *(us8*)&TbT[(size_t)(j0 + jj) * NDIM + i0 + ii0 + h * 8] = *(const us8*)&t[jj][ii0 + h * 8];
}

// ----------------------------------------------------------------
extern "C" void kernel_launch(void* const* d_in, const int* in_sizes, int n_in,
                              void* d_out, int out_size, void* d_ws, size_t ws_size,
                              hipStream_t stream) {
    const float* x = (const float*)d_in[0];   // [4096,1024]
    const float* y = (const float*)d_in[1];   // [4096,1024]

    float* out_aligned = (float*)d_out;                       // [4096,1024]
    float* Amat        = (float*)d_out + (size_t)MDIM * DDIM; // T region: holds A, then T in place

    // ws: xb 8MB | yb 8MB | xbT 8MB | KbT 32MB (TbT aliases after Sinkhorn) | u,v,inx,iny  == 56MB + 48KB
    unsigned short* xb  = (unsigned short*)d_ws;
    unsigned short* yb  = xb + (size_t)NDIM * DDIM;
    unsigned short* xbT = yb + (size_t)MDIM * DDIM;
    unsigned short* KbT = xbT + (size_t)NDIM * DDIM;
    unsigned short* TbT = KbT;                                 // alias: KbT dead after last v-step
    float* u   = (float*)(KbT + (size_t)NDIM * MDIM);
    float* v   = u + NDIM;
    float* inx = v + MDIM;
    float* iny = inx + NDIM;

    k_init_v<<<MDIM / 256, 256, 0, stream>>>(v);
    k_prep<<<(NDIM + MDIM) / 4, 256, 0, stream>>>(x, y, inx, iny, xb, yb);
    k_trans_cvt<DDIM, NDIM, 0><<<dim3(DDIM / 64, NDIM / 64), 256, 0, stream>>>(x, xbT);      // xbT[k][i] = bf16(x^T)
    k_gemm_nt<DDIM, MDIM, 1><<<dim3(MDIM / 128, NDIM / 128), 256, 0, stream>>>(xb, yb, inx, iny, Amat);
    k_trans_cvt<MDIM, NDIM, 1><<<dim3(MDIM / 64, NDIM / 64), 256, 0, stream>>>(Amat, KbT);   // KbT[j][i] = bf16(exp(A))^T

    for (int it = 0; it < NITER; ++it) {
        k_ustep<<<NDIM / 4, 256, 0, stream>>>(Amat, v, u);
        k_vstep<<<MDIM / 4, 256, 0, stream>>>(KbT, u, v);
    }

    k_epiT2<<<dim3(MDIM / 64, NDIM / 64), 256, 0, stream>>>(Amat, u, v, TbT);
    k_gemm_nt<NDIM, DDIM, 0><<<dim3(DDIM / 128, MDIM / 128), 256, 0, stream>>>(TbT, xbT, nullptr, nullptr, out_aligned);
}

// Round 7
// 521.937 us; speedup vs baseline: 1.2477x; 1.2477x over previous
//
#include <hip/hip_runtime.h>
#include <math.h>

#define NDIM 4096
#define MDIM 4096
#define DDIM 1024
#define NIT_CHEAP 14   // bf16-K both directions
#define NIT_POLISH 2   // fp32-A u-step: contracts cheap-operator fixed-point offset by 0.25^2 -> same fixed point as round-6

typedef float f4  __attribute__((ext_vector_type(4)));
typedef short s8v __attribute__((ext_vector_type(8)));          // 8 bf16 bit-patterns (4 VGPRs) - MFMA A/B frag
typedef unsigned short us4 __attribute__((ext_vector_type(4)));
typedef unsigned short us8 __attribute__((ext_vector_type(8)));

static __device__ __forceinline__ unsigned short f2bf(float f) {
    unsigned int u = __float_as_uint(f);
    unsigned int r = (u + 0x7FFFu + ((u >> 16) & 1u)) >> 16;   // RNE
    return (unsigned short)r;
}
static __device__ __forceinline__ float bf2f(unsigned int bits16) {
    return __uint_as_float(bits16 << 16);
}

// async global->LDS, 16B/lane: dest = wave-uniform base + lane*16 (m97 pattern).
// All casts go through integers (int->ptr casts always compile; LDS generic addr low 32b = LDS offset).
static __device__ __forceinline__ void stage16(const void* g, void* l) {
    __builtin_amdgcn_global_load_lds(
        (const __attribute__((address_space(1))) unsigned int*)(unsigned long long)g,
        (__attribute__((address_space(3))) unsigned int*)(unsigned int)(unsigned long long)l,
        16, 0, 0);
}

// ---------------------------------------------------------------- v = 1/m
__global__ __launch_bounds__(256) void k_init_v(float* __restrict__ v) {
    int i = blockIdx.x * 256 + threadIdx.x;
    if (i < MDIM) v[i] = 1.0f / (float)MDIM;
}

// ---------------------------------------------------------------- norms + bf16 convert (1 row/wave, rows 0..8191)
__global__ __launch_bounds__(256) void k_prep(const float* __restrict__ x, const float* __restrict__ y,
                                              float* __restrict__ inx, float* __restrict__ iny,
                                              unsigned short* __restrict__ xb, unsigned short* __restrict__ yb) {
    int row  = blockIdx.x * 4 + (threadIdx.x >> 6);
    int lane = threadIdx.x & 63;
    const float* src; float* dstn; unsigned short* dstb; int r;
    if (row < NDIM) { src = x; dstn = inx; dstb = xb; r = row; }
    else            { src = y; dstn = iny; dstb = yb; r = row - NDIM; }
    const f4* p = (const f4*)(src + (size_t)r * DDIM);
    float s = 0.0f;
    #pragma unroll
    for (int c = 0; c < 4; ++c) {
        f4 f = p[c * 64 + lane];
        s += f[0]*f[0] + f[1]*f[1] + f[2]*f[2] + f[3]*f[3];
        us4 h;
        #pragma unroll
        for (int e = 0; e < 4; ++e) h[e] = f2bf(f[e]);
        *(us4*)&dstb[(size_t)r * DDIM + (c * 64 + lane) * 4] = h;
    }
    #pragma unroll
    for (int off = 32; off; off >>= 1) s += __shfl_down(s, off, 64);
    if (lane == 0) dstn[r] = 1.0f / sqrtf(s);
}

// ---------------------------------------------------------------- transpose convert: dst[j][i] = bf16(src[i][j])
template<int SRCW, int DSTW>
__global__ __launch_bounds__(256) void k_trans_cvt(const float* __restrict__ src, unsigned short* __restrict__ dst) {
    __shared__ __align__(16) unsigned short t[64][72];
    const int i0 = blockIdx.y * 64, j0 = blockIdx.x * 64;
    const int r  = threadIdx.x >> 2;          // 0..63
    const int c0 = (threadIdx.x & 3) * 16;    // 0,16,32,48
    #pragma unroll
    for (int q = 0; q < 4; ++q) {
        f4 f = *(const f4*)&src[(size_t)(i0 + r) * SRCW + j0 + c0 + q * 4];
        #pragma unroll
        for (int e = 0; e < 4; ++e) t[c0 + q * 4 + e][r] = f2bf(f[e]);
    }
    __syncthreads();
    const int jj  = threadIdx.x >> 2;
    const int ii0 = (threadIdx.x & 3) * 16;
    #pragma unroll
    for (int h = 0; h < 2; ++h)
        *(us8*)&dst[(size_t)(j0 + jj) * DSTW + i0 + ii0 + h * 8] = *(const us8*)&t[jj][ii0 + h * 8];
}

// ---------------------------------------------------------------- Kb = bf16(exp(A)) row-major AND KbT = transpose
__global__ __launch_bounds__(256) void k_exp_both(const float* __restrict__ A,
                                                  unsigned short* __restrict__ Kb,
                                                  unsigned short* __restrict__ KbT) {
    __shared__ __align__(16) unsigned short t[64][72];
    const int i0 = blockIdx.y * 64, j0 = blockIdx.x * 64;
    const int r  = threadIdx.x >> 2;
    const int c0 = (threadIdx.x & 3) * 16;
    unsigned short hs[16];
    #pragma unroll
    for (int q = 0; q < 4; ++q) {
        f4 f = *(const f4*)&A[(size_t)(i0 + r) * MDIM + j0 + c0 + q * 4];
        #pragma unroll
        for (int e = 0; e < 4; ++e) hs[q * 4 + e] = f2bf(expf(f[e]));
    }
    #pragma unroll
    for (int h = 0; h < 2; ++h) {
        us8 pack;
        #pragma unroll
        for (int w = 0; w < 8; ++w) pack[w] = hs[h * 8 + w];
        *(us8*)&Kb[(size_t)(i0 + r) * MDIM + j0 + c0 + h * 8] = pack;
    }
    #pragma unroll
    for (int j = 0; j < 16; ++j) t[c0 + j][r] = hs[j];
    __syncthreads();
    const int jj  = threadIdx.x >> 2;
    const int ii0 = (threadIdx.x & 3) * 16;
    #pragma unroll
    for (int h = 0; h < 2; ++h)
        *(us8*)&KbT[(size_t)(j0 + jj) * NDIM + i0 + ii0 + h * 8] = *(const us8*)&t[jj][ii0 + h * 8];
}

// ---------------------------------------------------------------- bf16 NT MFMA GEMM, m97 structure:
// 128x128 tile, 4 waves (2x2), BK=64, LINEAR LDS [128][64] staged via global_load_lds width=16
template<int KDIM, int CSTRIDE, int SCALE>
__global__ __launch_bounds__(256) void k_gemm_nt(const unsigned short* __restrict__ Amat,
                                                 const unsigned short* __restrict__ Bmat,
                                                 const float* __restrict__ scA, const float* __restrict__ scB,
                                                 float* __restrict__ C) {
    __shared__ __align__(16) short xs[128 * 64];
    __shared__ __align__(16) short ys[128 * 64];
    const int tid  = threadIdx.x;
    const int wave = tid >> 6, lane = tid & 63;
    const int wr = wave >> 1, wc = wave & 1;          // 2x2 wave grid
    const int i0 = blockIdx.y * 128;
    const int j0 = blockIdx.x * 128;
    f4 acc[4][4];
    #pragma unroll
    for (int a = 0; a < 4; ++a)
        #pragma unroll
        for (int b = 0; b < 4; ++b) acc[a][b] = (f4)0.0f;

    const int lrow8 = lane >> 3;        // 0..7: row within 8-row staging chunk
    const int lcol  = (lane & 7) * 8;   // bf16 element col within 64-wide row
    const int frow = lane & 15;         // A-row / B-col within 16-tile
    const int fkg  = lane >> 4;         // k-group 0..3 (8 bf16 each)

    for (int k0 = 0; k0 < KDIM; k0 += 64) {
        __syncthreads();   // previous iter's LDS reads complete before overwrite
        #pragma unroll
        for (int q = 0; q < 4; ++q) {
            const int r0 = wave * 32 + q * 8;   // wave-uniform chunk base row
            stage16(&Amat[(size_t)(i0 + r0 + lrow8) * KDIM + k0 + lcol], &xs[r0 * 64]);
            stage16(&Bmat[(size_t)(j0 + r0 + lrow8) * KDIM + k0 + lcol], &ys[r0 * 64]);
        }
        __syncthreads();   // drains vmcnt(0): staged data visible
        #pragma unroll
        for (int ks = 0; ks < 2; ++ks) {
            s8v af[4], bfr[4];
            #pragma unroll
            for (int t = 0; t < 4; ++t)
                af[t]  = *(const s8v*)&xs[(wr * 64 + t * 16 + frow) * 64 + ks * 32 + fkg * 8];
            #pragma unroll
            for (int t = 0; t < 4; ++t)
                bfr[t] = *(const s8v*)&ys[(wc * 64 + t * 16 + frow) * 64 + ks * 32 + fkg * 8];
            #pragma unroll
            for (int mr = 0; mr < 4; ++mr)
                #pragma unroll
                for (int nc = 0; nc < 4; ++nc)
                    acc[mr][nc] = __builtin_amdgcn_mfma_f32_16x16x32_bf16(af[mr], bfr[nc], acc[mr][nc], 0, 0, 0);
        }
    }
    // C/D layout (HW-verified m89): col = lane&15, row = (lane>>4)*4 + reg
    const int lr2 = (lane >> 4) * 4;
    const int lc2 = lane & 15;
    #pragma unroll
    for (int nc = 0; nc < 4; ++nc) {
        int jb = j0 + wc * 64 + nc * 16 + lc2;
        float sb = SCALE ? scB[jb] : 1.0f;
        #pragma unroll
        for (int mr = 0; mr < 4; ++mr) {
            #pragma unroll
            for (int r = 0; r < 4; ++r) {
                int ib = i0 + wr * 64 + mr * 16 + lr2 + r;
                float val = acc[mr][nc][r];
                if (SCALE) val *= scA[ib] * sb;
                C[(size_t)ib * CSTRIDE + jb] = val;
            }
        }
    }
}

// ---------------------------------------------------------------- bf16 GEMV step: out = sqrt((1/4096) / (Kmat @ vin))
__global__ __launch_bounds__(256) void k_vstep(const unsigned short* __restrict__ Kmat,
                                               const float* __restrict__ vin, float* __restrict__ vout) {
    const int row  = blockIdx.x * 4 + (threadIdx.x >> 6);
    const int lane = threadIdx.x & 63;
    const unsigned short* Krow = Kmat + (size_t)row * NDIM;
    float acc = 0.0f;
    #pragma unroll
    for (int c = 0; c < 8; ++c) {
        int j = (c * 64 + lane) * 8;
        us8 kq = *(const us8*)&Krow[j];
        f4 ua = *(const f4*)&vin[j];
        f4 ub = *(const f4*)&vin[j + 4];
        acc += bf2f(kq[0])*ua[0] + bf2f(kq[1])*ua[1] + bf2f(kq[2])*ua[2] + bf2f(kq[3])*ua[3]
             + bf2f(kq[4])*ub[0] + bf2f(kq[5])*ub[1] + bf2f(kq[6])*ub[2] + bf2f(kq[7])*ub[3];
    }
    #pragma unroll
    for (int off = 32; off; off >>= 1) acc += __shfl_xor(acc, off, 64);
    if (lane == 0) vout[row] = sqrtf((1.0f / 4096.0f) / acc);
}

// ---------------------------------------------------------------- polish u-step: u = sqrt((1/4096) / (exp(A) @ v)), fp32 A
__global__ __launch_bounds__(256) void k_ustep(const float* __restrict__ Amat,
                                               const float* __restrict__ vin, float* __restrict__ uout) {
    const int row  = blockIdx.x * 4 + (threadIdx.x >> 6);
    const int lane = threadIdx.x & 63;
    const float* Arow = Amat + (size_t)row * MDIM;
    double acc = 0.0;
    #pragma unroll
    for (int c = 0; c < 16; ++c) {
        int j = (c * 64 + lane) * 4;
        f4 a = *(const f4*)&Arow[j];
        f4 v = *(const f4*)&vin[j];
        acc += (double)(expf(a[0])*v[0] + expf(a[1])*v[1] + expf(a[2])*v[2] + expf(a[3])*v[3]);
    }
    #pragma unroll
    for (int off = 32; off; off >>= 1) acc += __shfl_xor(acc, off, 64);
    if (lane == 0) uout[row] = (float)sqrt((1.0 / 4096.0) / acc);
}

// ---------------------------------------------------------------- T = A*u_i*exp(A)*v_j in place + TbT = bf16(T^T)
__global__ __launch_bounds__(256) void k_epiT2(float* __restrict__ Am,
                                               const float* __restrict__ u, const float* __restrict__ v,
                                               unsigned short* __restrict__ TbT) {
    __shared__ __align__(16) unsigned short t[64][72];
    const int i0 = blockIdx.y * 64, j0 = blockIdx.x * 64;
    const int r  = threadIdx.x >> 2;
    const int c0 = (threadIdx.x & 3) * 16;
    const float ui = u[i0 + r];
    #pragma unroll
    for (int q = 0; q < 4; ++q) {
        f4 a  = *(const f4*)&Am[(size_t)(i0 + r) * MDIM + j0 + c0 + q * 4];
        f4 vv = *(const f4*)&v[j0 + c0 + q * 4];
        f4 tt;
        #pragma unroll
        for (int e = 0; e < 4; ++e) tt[e] = a[e] * ui * expf(a[e]) * vv[e];
        *(f4*)&Am[(size_t)(i0 + r) * MDIM + j0 + c0 + q * 4] = tt;
        #pragma unroll
        for (int e = 0; e < 4; ++e) t[c0 + q * 4 + e][r] = f2bf(tt[e]);
    }
    __syncthreads();
    const int jj  = threadIdx.x >> 2;
    const int ii0 = (threadIdx.x & 3) * 16;
    #pragma unroll
    for (int h = 0; h < 2; ++h)
        *(us8*)&TbT[(size_t)(j0 + jj) * NDIM + i0 + ii0 + h * 8] = *(const us8*)&t[jj][ii0 + h * 8];
}

// ----------------------------------------------------------------
extern "C" void kernel_launch(void* const* d_in, const int* in_sizes, int n_in,
                              void* d_out, int out_size, void* d_ws, size_t ws_size,
                              hipStream_t stream) {
    const float* x = (const float*)d_in[0];   // [4096,1024]
    const float* y = (const float*)d_in[1];   // [4096,1024]

    float* out_aligned = (float*)d_out;                       // [4096,1024]
    float* Amat        = (float*)d_out + (size_t)MDIM * DDIM; // T region: holds A, then T in place

    // ws phase map (64 MB + 64 KB total, same footprint as the round-1-proven layout):
    //   phase 1: [xb 8MB][yb 8MB]                 (dead after cos-GEMM)
    //   phase 2: [Kb 32MB][KbT 32MB]              (Kb overwrites xb/yb)
    //   phase 3: [TbT 32MB over Kb][xbT 8MB over KbT]
    unsigned short* xb  = (unsigned short*)d_ws;
    unsigned short* yb  = xb + (size_t)NDIM * DDIM;
    unsigned short* Kb  = (unsigned short*)d_ws;
    unsigned short* KbT = Kb + (size_t)NDIM * MDIM;
    unsigned short* TbT = Kb;
    unsigned short* xbT = KbT;
    float* u   = (float*)(KbT + (size_t)NDIM * MDIM);
    float* v   = u + NDIM;
    float* inx = v + MDIM;
    float* iny = inx + NDIM;

    k_init_v<<<MDIM / 256, 256, 0, stream>>>(v);
    k_prep<<<(NDIM + MDIM) / 4, 256, 0, stream>>>(x, y, inx, iny, xb, yb);
    k_gemm_nt<DDIM, MDIM, 1><<<dim3(MDIM / 128, NDIM / 128), 256, 0, stream>>>(xb, yb, inx, iny, Amat);
    k_exp_both<<<dim3(MDIM / 64, NDIM / 64), 256, 0, stream>>>(Amat, Kb, KbT);   // overwrites xb/yb

    for (int it = 0; it < NIT_CHEAP; ++it) {
        k_vstep<<<NDIM / 4, 256, 0, stream>>>(Kb,  v, u);   // u = sqrt(a / (K  v)), bf16
        k_vstep<<<MDIM / 4, 256, 0, stream>>>(KbT, u, v);   // v = sqrt(b / (K^T u)), bf16
    }
    for (int it = 0; it < NIT_POLISH; ++it) {
        k_ustep<<<NDIM / 4, 256, 0, stream>>>(Amat, v, u);  // fp32-exp(A) u-step: same operator as round-6
        k_vstep<<<MDIM / 4, 256, 0, stream>>>(KbT, u, v);
    }

    k_trans_cvt<DDIM, NDIM><<<dim3(DDIM / 64, NDIM / 64), 256, 0, stream>>>(x, xbT);  // over dead KbT
    k_epiT2<<<dim3(MDIM / 64, NDIM / 64), 256, 0, stream>>>(Amat, u, v, TbT);         // over dead Kb
    k_gemm_nt<NDIM, DDIM, 0><<<dim3(DDIM / 128, MDIM / 128), 256, 0, stream>>>(TbT, xbT, nullptr, nullptr, out_aligned);
}

// Round 8
// 415.226 us; speedup vs baseline: 1.5683x; 1.2570x over previous
//
#include <hip/hip_runtime.h>
#include <math.h>

#define NDIM 4096
#define MDIM 4096
#define DDIM 1024
#define NITER 10   // contraction fi^2=0.25/iter; residual ~3e-6 rel on u,v -> ~1e-9 on output (floor is bf16 GEMM, see r6/r7 identical absmax)

typedef float f4  __attribute__((ext_vector_type(4)));
typedef short s8v __attribute__((ext_vector_type(8)));          // 8 bf16 bit-patterns (4 VGPRs) - MFMA A/B frag
typedef unsigned short us4 __attribute__((ext_vector_type(4)));
typedef unsigned short us8 __attribute__((ext_vector_type(8)));

static __device__ __forceinline__ unsigned short f2bf(float f) {
    unsigned int u = __float_as_uint(f);
    unsigned int r = (u + 0x7FFFu + ((u >> 16) & 1u)) >> 16;   // RNE
    return (unsigned short)r;
}
static __device__ __forceinline__ float bf2f(unsigned int bits16) {
    return __uint_as_float(bits16 << 16);
}

// async global->LDS, 16B/lane: dest = wave-uniform base + lane*16 (m97 pattern).
static __device__ __forceinline__ void stage16(const void* g, void* l) {
    __builtin_amdgcn_global_load_lds(
        (const __attribute__((address_space(1))) unsigned int*)(unsigned long long)g,
        (__attribute__((address_space(3))) unsigned int*)(unsigned int)(unsigned long long)l,
        16, 0, 0);
}

// ---------------------------------------------------------------- v = 1/m
__global__ __launch_bounds__(256) void k_init_v(float* __restrict__ v) {
    int i = blockIdx.x * 256 + threadIdx.x;
    if (i < MDIM) v[i] = 1.0f / (float)MDIM;
}

// ---------------------------------------------------------------- norms + bf16 convert (1 row/wave, rows 0..8191)
__global__ __launch_bounds__(256) void k_prep(const float* __restrict__ x, const float* __restrict__ y,
                                              float* __restrict__ inx, float* __restrict__ iny,
                                              unsigned short* __restrict__ xb, unsigned short* __restrict__ yb) {
    int row  = blockIdx.x * 4 + (threadIdx.x >> 6);
    int lane = threadIdx.x & 63;
    const float* src; float* dstn; unsigned short* dstb; int r;
    if (row < NDIM) { src = x; dstn = inx; dstb = xb; r = row; }
    else            { src = y; dstn = iny; dstb = yb; r = row - NDIM; }
    const f4* p = (const f4*)(src + (size_t)r * DDIM);
    float s = 0.0f;
    #pragma unroll
    for (int c = 0; c < 4; ++c) {
        f4 f = p[c * 64 + lane];
        s += f[0]*f[0] + f[1]*f[1] + f[2]*f[2] + f[3]*f[3];
        us4 h;
        #pragma unroll
        for (int e = 0; e < 4; ++e) h[e] = f2bf(f[e]);
        *(us4*)&dstb[(size_t)r * DDIM + (c * 64 + lane) * 4] = h;
    }
    #pragma unroll
    for (int off = 32; off; off >>= 1) s += __shfl_down(s, off, 64);
    if (lane == 0) dstn[r] = 1.0f / sqrtf(s);
}

// ---------------------------------------------------------------- transpose convert: dst[j][i] = bf16(src[i][j])
template<int SRCW, int DSTW>
__global__ __launch_bounds__(256) void k_trans_cvt(const float* __restrict__ src, unsigned short* __restrict__ dst) {
    __shared__ __align__(16) unsigned short t[64][72];
    const int i0 = blockIdx.y * 64, j0 = blockIdx.x * 64;
    const int r  = threadIdx.x >> 2;          // 0..63
    const int c0 = (threadIdx.x & 3) * 16;    // 0,16,32,48
    #pragma unroll
    for (int q = 0; q < 4; ++q) {
        f4 f = *(const f4*)&src[(size_t)(i0 + r) * SRCW + j0 + c0 + q * 4];
        #pragma unroll
        for (int e = 0; e < 4; ++e) t[c0 + q * 4 + e][r] = f2bf(f[e]);
    }
    __syncthreads();
    const int jj  = threadIdx.x >> 2;
    const int ii0 = (threadIdx.x & 3) * 16;
    #pragma unroll
    for (int h = 0; h < 2; ++h)
        *(us8*)&dst[(size_t)(j0 + jj) * DSTW + i0 + ii0 + h * 8] = *(const us8*)&t[jj][ii0 + h * 8];
}

// ---------------------------------------------------------------- Kb = bf16(exp(A)) row-major AND KbT = transpose
__global__ __launch_bounds__(256) void k_exp_both(const float* __restrict__ A,
                                                  unsigned short* __restrict__ Kb,
                                                  unsigned short* __restrict__ KbT) {
    __shared__ __align__(16) unsigned short t[64][72];
    const int i0 = blockIdx.y * 64, j0 = blockIdx.x * 64;
    const int r  = threadIdx.x >> 2;
    const int c0 = (threadIdx.x & 3) * 16;
    unsigned short hs[16];
    #pragma unroll
    for (int q = 0; q < 4; ++q) {
        f4 f = *(const f4*)&A[(size_t)(i0 + r) * MDIM + j0 + c0 + q * 4];
        #pragma unroll
        for (int e = 0; e < 4; ++e) hs[q * 4 + e] = f2bf(expf(f[e]));
    }
    #pragma unroll
    for (int h = 0; h < 2; ++h) {
        us8 pack;
        #pragma unroll
        for (int w = 0; w < 8; ++w) pack[w] = hs[h * 8 + w];
        *(us8*)&Kb[(size_t)(i0 + r) * MDIM + j0 + c0 + h * 8] = pack;
    }
    #pragma unroll
    for (int j = 0; j < 16; ++j) t[c0 + j][r] = hs[j];
    __syncthreads();
    const int jj  = threadIdx.x >> 2;
    const int ii0 = (threadIdx.x & 3) * 16;
    #pragma unroll
    for (int h = 0; h < 2; ++h)
        *(us8*)&KbT[(size_t)(j0 + jj) * NDIM + i0 + ii0 + h * 8] = *(const us8*)&t[jj][ii0 + h * 8];
}

// ---------------------------------------------------------------- bf16 NT MFMA GEMM, m97 structure + chunk-XOR swizzle:
// 128x128 tile, 4 waves (2x2), BK=64, linear LDS [128][64] via global_load_lds(16B).
// Swizzle (rule #21, both-sides): LDS[row][chunk] holds global chunk (chunk ^ (row&7));
// source address pre-swizzled, frag read XORs back -> ds_read_b128 spreads all 32 banks.
template<int KDIM, int CSTRIDE, int SCALE>
__global__ __launch_bounds__(256) void k_gemm_nt(const unsigned short* __restrict__ Amat,
                                                 const unsigned short* __restrict__ Bmat,
                                                 const float* __restrict__ scA, const float* __restrict__ scB,
                                                 float* __restrict__ C) {
    __shared__ __align__(16) short xs[128 * 64];
    __shared__ __align__(16) short ys[128 * 64];
    const int tid  = threadIdx.x;
    const int wave = tid >> 6, lane = tid & 63;
    const int wr = wave >> 1, wc = wave & 1;          // 2x2 wave grid
    const int i0 = blockIdx.y * 128;
    const int j0 = blockIdx.x * 128;
    f4 acc[4][4];
    #pragma unroll
    for (int a = 0; a < 4; ++a)
        #pragma unroll
        for (int b = 0; b < 4; ++b) acc[a][b] = (f4)0.0f;

    const int lrow8 = lane >> 3;               // 0..7: row within 8-row staging chunk
    const int scc   = ((lane & 7) ^ lrow8) * 8;// pre-swizzled source bf16 col (chunk ^ row&7)
    const int frow  = lane & 15;               // A-row / B-col within 16-tile
    const int fkg   = lane >> 4;               // k-group 0..3 (8 bf16 each)
    const int fs    = frow & 7;                // read-side XOR key

    for (int k0 = 0; k0 < KDIM; k0 += 64) {
        __syncthreads();   // previous iter's LDS reads complete before overwrite
        #pragma unroll
        for (int q = 0; q < 4; ++q) {
            const int r0 = wave * 32 + q * 8;   // wave-uniform chunk base row
            stage16(&Amat[(size_t)(i0 + r0 + lrow8) * KDIM + k0 + scc], &xs[r0 * 64]);
            stage16(&Bmat[(size_t)(j0 + r0 + lrow8) * KDIM + k0 + scc], &ys[r0 * 64]);
        }
        __syncthreads();   // drains vmcnt(0): staged data visible
        #pragma unroll
        for (int ks = 0; ks < 2; ++ks) {
            const int rc = ((ks * 4 + fkg) ^ fs) * 8;   // swizzled read col
            s8v af[4], bfr[4];
            #pragma unroll
            for (int t = 0; t < 4; ++t)
                af[t]  = *(const s8v*)&xs[(wr * 64 + t * 16 + frow) * 64 + rc];
            #pragma unroll
            for (int t = 0; t < 4; ++t)
                bfr[t] = *(const s8v*)&ys[(wc * 64 + t * 16 + frow) * 64 + rc];
            #pragma unroll
            for (int mr = 0; mr < 4; ++mr)
                #pragma unroll
                for (int nc = 0; nc < 4; ++nc)
                    acc[mr][nc] = __builtin_amdgcn_mfma_f32_16x16x32_bf16(af[mr], bfr[nc], acc[mr][nc], 0, 0, 0);
        }
    }
    // C/D layout (HW-verified m89): col = lane&15, row = (lane>>4)*4 + reg
    const int lr2 = (lane >> 4) * 4;
    const int lc2 = lane & 15;
    #pragma unroll
    for (int nc = 0; nc < 4; ++nc) {
        int jb = j0 + wc * 64 + nc * 16 + lc2;
        float sb = SCALE ? scB[jb] : 1.0f;
        #pragma unroll
        for (int mr = 0; mr < 4; ++mr) {
            #pragma unroll
            for (int r = 0; r < 4; ++r) {
                int ib = i0 + wr * 64 + mr * 16 + lr2 + r;
                float val = acc[mr][nc][r];
                if (SCALE) val *= scA[ib] * sb;
                C[(size_t)ib * CSTRIDE + jb] = val;
            }
        }
    }
}

// ---------------------------------------------------------------- bf16 GEMV step: out = sqrt((1/4096) / (Kmat @ vin))
__global__ __launch_bounds__(256) void k_vstep(const unsigned short* __restrict__ Kmat,
                                               const float* __restrict__ vin, float* __restrict__ vout) {
    const int row  = blockIdx.x * 4 + (threadIdx.x >> 6);
    const int lane = threadIdx.x & 63;
    const unsigned short* Krow = Kmat + (size_t)row * NDIM;
    float acc = 0.0f;
    #pragma unroll
    for (int c = 0; c < 8; ++c) {
        int j = (c * 64 + lane) * 8;
        us8 kq = *(const us8*)&Krow[j];
        f4 ua = *(const f4*)&vin[j];
        f4 ub = *(const f4*)&vin[j + 4];
        acc += bf2f(kq[0])*ua[0] + bf2f(kq[1])*ua[1] + bf2f(kq[2])*ua[2] + bf2f(kq[3])*ua[3]
             + bf2f(kq[4])*ub[0] + bf2f(kq[5])*ub[1] + bf2f(kq[6])*ub[2] + bf2f(kq[7])*ub[3];
    }
    #pragma unroll
    for (int off = 32; off; off >>= 1) acc += __shfl_xor(acc, off, 64);
    if (lane == 0) vout[row] = sqrtf((1.0f / 4096.0f) / acc);
}

// ---------------------------------------------------------------- T = A*u_i*exp(A)*v_j in place + TbT = bf16(T^T)
__global__ __launch_bounds__(256) void k_epiT2(float* __restrict__ Am,
                                               const float* __restrict__ u, const float* __restrict__ v,
                                               unsigned short* __restrict__ TbT) {
    __shared__ __align__(16) unsigned short t[64][72];
    const int i0 = blockIdx.y * 64, j0 = blockIdx.x * 64;
    const int r  = threadIdx.x >> 2;
    const int c0 = (threadIdx.x & 3) * 16;
    const float ui = u[i0 + r];
    #pragma unroll
    for (int q = 0; q < 4; ++q) {
        f4 a  = *(const f4*)&Am[(size_t)(i0 + r) * MDIM + j0 + c0 + q * 4];
        f4 vv = *(const f4*)&v[j0 + c0 + q * 4];
        f4 tt;
        #pragma unroll
        for (int e = 0; e < 4; ++e) tt[e] = a[e] * ui * expf(a[e]) * vv[e];
        *(f4*)&Am[(size_t)(i0 + r) * MDIM + j0 + c0 + q * 4] = tt;
        #pragma unroll
        for (int e = 0; e < 4; ++e) t[c0 + q * 4 + e][r] = f2bf(tt[e]);
    }
    __syncthreads();
    const int jj  = threadIdx.x >> 2;
    const int ii0 = (threadIdx.x & 3) * 16;
    #pragma unroll
    for (int h = 0; h < 2; ++h)
        *(us8*)&TbT[(size_t)(j0 + jj) * NDIM + i0 + ii0 + h * 8] = *(const us8*)&t[jj][ii0 + h * 8];
}

// ----------------------------------------------------------------
extern "C" void kernel_launch(void* const* d_in, const int* in_sizes, int n_in,
                              void* d_out, int out_size, void* d_ws, size_t ws_size,
                              hipStream_t stream) {
    const float* x = (const float*)d_in[0];   // [4096,1024]
    const float* y = (const float*)d_in[1];   // [4096,1024]

    float* out_aligned = (float*)d_out;                       // [4096,1024]
    float* Amat        = (float*)d_out + (size_t)MDIM * DDIM; // T region: holds A, then T in place

    // ws phase map (64 MB + 64 KB):
    //   phase 1: [xb 8MB][yb 8MB]                 (dead after cos-GEMM)
    //   phase 2: [Kb 32MB][KbT 32MB]              (Kb overwrites xb/yb)
    //   phase 3: [TbT 32MB over Kb][xbT 8MB over KbT]
    unsigned short* xb  = (unsigned short*)d_ws;
    unsigned short* yb  = xb + (size_t)NDIM * DDIM;
    unsigned short* Kb  = (unsigned short*)d_ws;
    unsigned short* KbT = Kb + (size_t)NDIM * MDIM;
    unsigned short* TbT = Kb;
    unsigned short* xbT = KbT;
    float* u   = (float*)(KbT + (size_t)NDIM * MDIM);
    float* v   = u + NDIM;
    float* inx = v + MDIM;
    float* iny = inx + NDIM;

    k_init_v<<<MDIM / 256, 256, 0, stream>>>(v);
    k_prep<<<(NDIM + MDIM) / 4, 256, 0, stream>>>(x, y, inx, iny, xb, yb);
    k_gemm_nt<DDIM, MDIM, 1><<<dim3(MDIM / 128, NDIM / 128), 256, 0, stream>>>(xb, yb, inx, iny, Amat);
    k_exp_both<<<dim3(MDIM / 64, NDIM / 64), 256, 0, stream>>>(Amat, Kb, KbT);   // overwrites xb/yb

    for (int it = 0; it < NITER; ++it) {
        k_vstep<<<NDIM / 4, 256, 0, stream>>>(Kb,  v, u);   // u = sqrt(a / (K  v)), bf16
        k_vstep<<<MDIM / 4, 256, 0, stream>>>(KbT, u, v);   // v = sqrt(b / (K^T u)), bf16
    }

    k_trans_cvt<DDIM, NDIM><<<dim3(DDIM / 64, NDIM / 64), 256, 0, stream>>>(x, xbT);  // over dead KbT
    k_epiT2<<<dim3(MDIM / 64, NDIM / 64), 256, 0, stream>>>(Amat, u, v, TbT);         // over dead Kb
    k_gemm_nt<NDIM, DDIM, 0><<<dim3(DDIM / 128, MDIM / 128), 256, 0, stream>>>(TbT, xbT, nullptr, nullptr, out_aligned);
}

// Round 10
// 374.282 us; speedup vs baseline: 1.7399x; 1.1094x over previous
//
#include <hip/hip_runtime.h>
#include <math.h>

#define NDIM 4096
#define MDIM 4096
#define DDIM 1024
#define NITER 8   // r7(16it) vs r8(10it): bit-identical absmax => Sinkhorn residual << floor; 8 iters bounds it <2e-7

typedef float f4  __attribute__((ext_vector_type(4)));
typedef short s8v __attribute__((ext_vector_type(8)));          // 8 bf16 bit-patterns (4 VGPRs) - MFMA A/B frag
typedef unsigned short us4 __attribute__((ext_vector_type(4)));
typedef unsigned short us8 __attribute__((ext_vector_type(8)));

static __device__ __forceinline__ unsigned short f2bf(float f) {
    unsigned int u = __float_as_uint(f);
    unsigned int r = (u + 0x7FFFu + ((u >> 16) & 1u)) >> 16;   // RNE
    return (unsigned short)r;
}
static __device__ __forceinline__ float bf2f(unsigned int bits16) {
    return __uint_as_float(bits16 << 16);
}

// async global->LDS, 16B/lane: dest = wave-uniform base + lane*16 (m97 pattern).
static __device__ __forceinline__ void stage16(const void* g, void* l) {
    __builtin_amdgcn_global_load_lds(
        (const __attribute__((address_space(1))) unsigned int*)(unsigned long long)g,
        (__attribute__((address_space(3))) unsigned int*)(unsigned int)(unsigned long long)l,
        16, 0, 0);
}

// ---------------------------------------------------------------- v = 1/m
__global__ __launch_bounds__(256) void k_init_v(float* __restrict__ v) {
    int i = blockIdx.x * 256 + threadIdx.x;
    if (i < MDIM) v[i] = 1.0f / (float)MDIM;
}

// ---------------------------------------------------------------- norms + bf16 convert (1 row/wave, rows 0..8191)
__global__ __launch_bounds__(256) void k_prep(const float* __restrict__ x, const float* __restrict__ y,
                                              float* __restrict__ inx, float* __restrict__ iny,
                                              unsigned short* __restrict__ xb, unsigned short* __restrict__ yb) {
    int row  = blockIdx.x * 4 + (threadIdx.x >> 6);
    int lane = threadIdx.x & 63;
    const float* src; float* dstn; unsigned short* dstb; int r;
    if (row < NDIM) { src = x; dstn = inx; dstb = xb; r = row; }
    else            { src = y; dstn = iny; dstb = yb; r = row - NDIM; }
    const f4* p = (const f4*)(src + (size_t)r * DDIM);
    float s = 0.0f;
    #pragma unroll
    for (int c = 0; c < 4; ++c) {
        f4 f = p[c * 64 + lane];
        s += f[0]*f[0] + f[1]*f[1] + f[2]*f[2] + f[3]*f[3];
        us4 h;
        #pragma unroll
        for (int e = 0; e < 4; ++e) h[e] = f2bf(f[e]);
        *(us4*)&dstb[(size_t)r * DDIM + (c * 64 + lane) * 4] = h;
    }
    #pragma unroll
    for (int off = 32; off; off >>= 1) s += __shfl_down(s, off, 64);
    if (lane == 0) dstn[r] = 1.0f / sqrtf(s);
}

// ---------------------------------------------------------------- transpose convert: dst[j][i] = bf16(src[i][j])
template<int SRCW, int DSTW>
__global__ __launch_bounds__(256) void k_trans_cvt(const float* __restrict__ src, unsigned short* __restrict__ dst) {
    __shared__ __align__(16) unsigned short t[64][72];
    const int i0 = blockIdx.y * 64, j0 = blockIdx.x * 64;
    const int r  = threadIdx.x >> 2;          // 0..63
    const int c0 = (threadIdx.x & 3) * 16;    // 0,16,32,48
    #pragma unroll
    for (int q = 0; q < 4; ++q) {
        f4 f = *(const f4*)&src[(size_t)(i0 + r) * SRCW + j0 + c0 + q * 4];
        #pragma unroll
        for (int e = 0; e < 4; ++e) t[c0 + q * 4 + e][r] = f2bf(f[e]);
    }
    __syncthreads();
    const int jj  = threadIdx.x >> 2;
    const int ii0 = (threadIdx.x & 3) * 16;
    #pragma unroll
    for (int h = 0; h < 2; ++h)
        *(us8*)&dst[(size_t)(j0 + jj) * DSTW + i0 + ii0 + h * 8] = *(const us8*)&t[jj][ii0 + h * 8];
}

// ---------------------------------------------------------------- Kb = bf16(exp(A)) row-major AND KbT = transpose
__global__ __launch_bounds__(256) void k_exp_both(const float* __restrict__ A,
                                                  unsigned short* __restrict__ Kb,
                                                  unsigned short* __restrict__ KbT) {
    __shared__ __align__(16) unsigned short t[64][72];
    const int i0 = blockIdx.y * 64, j0 = blockIdx.x * 64;
    const int r  = threadIdx.x >> 2;
    const int c0 = (threadIdx.x & 3) * 16;
    unsigned short hs[16];
    #pragma unroll
    for (int q = 0; q < 4; ++q) {
        f4 f = *(const f4*)&A[(size_t)(i0 + r) * MDIM + j0 + c0 + q * 4];
        #pragma unroll
        for (int e = 0; e < 4; ++e) hs[q * 4 + e] = f2bf(expf(f[e]));
    }
    #pragma unroll
    for (int h = 0; h < 2; ++h) {
        us8 pack;
        #pragma unroll
        for (int w = 0; w < 8; ++w) pack[w] = hs[h * 8 + w];
        *(us8*)&Kb[(size_t)(i0 + r) * MDIM + j0 + c0 + h * 8] = pack;
    }
    #pragma unroll
    for (int j = 0; j < 16; ++j) t[c0 + j][r] = hs[j];
    __syncthreads();
    const int jj  = threadIdx.x >> 2;
    const int ii0 = (threadIdx.x & 3) * 16;
    #pragma unroll
    for (int h = 0; h < 2; ++h)
        *(us8*)&KbT[(size_t)(j0 + jj) * NDIM + i0 + ii0 + h * 8] = *(const us8*)&t[jj][ii0 + h * 8];
}

// ---------------------------------------------------------------- bf16 NT MFMA GEMM, m97 structure + chunk-XOR swizzle.
// 128x128 tile, 4 waves (2x2), BK=64, linear LDS via global_load_lds(16B), pre-swizzled source + swizzled read.
// DBUF=1: 2-phase double-buffer with raw s_barrier + counted vmcnt (prefetch survives the barrier).
// ATOMIC=1: split-K over blockIdx.z (KLEN per block), unsafeAtomicAdd into pre-zeroed C.
template<int LDK, int KLEN, int CSTRIDE, int SCALE, int DBUF, int ATOMIC>
__global__ __launch_bounds__(256) void k_gemm_nt(const unsigned short* __restrict__ Amat,
                                                 const unsigned short* __restrict__ Bmat,
                                                 const float* __restrict__ scA, const float* __restrict__ scB,
                                                 float* __restrict__ C) {
    __shared__ __align__(16) short xs[DBUF ? 2 : 1][128 * 64];
    __shared__ __align__(16) short ys[DBUF ? 2 : 1][128 * 64];
    const int tid  = threadIdx.x;
    const int wave = tid >> 6, lane = tid & 63;
    const int wr = wave >> 1, wc = wave & 1;          // 2x2 wave grid
    const int i0 = blockIdx.y * 128;
    const int j0 = blockIdx.x * 128;
    const int koff = ATOMIC ? blockIdx.z * KLEN : 0;
    f4 acc[4][4];
    #pragma unroll
    for (int a = 0; a < 4; ++a)
        #pragma unroll
        for (int b = 0; b < 4; ++b) acc[a][b] = (f4)0.0f;

    const int lrow8 = lane >> 3;               // 0..7: row within 8-row staging chunk
    const int scc   = ((lane & 7) ^ lrow8) * 8;// pre-swizzled source bf16 col (chunk ^ row&7)
    const int frow  = lane & 15;               // A-row / B-col within 16-tile
    const int fkg   = lane >> 4;               // k-group 0..3 (8 bf16 each)
    const int fs    = frow & 7;                // read-side XOR key

    auto stage_tile = [&](int k0, int buf) {
        #pragma unroll
        for (int q = 0; q < 4; ++q) {
            const int r0 = wave * 32 + q * 8;   // wave-uniform chunk base row
            stage16(&Amat[(size_t)(i0 + r0 + lrow8) * LDK + koff + k0 + scc], &xs[buf][r0 * 64]);
            stage16(&Bmat[(size_t)(j0 + r0 + lrow8) * LDK + koff + k0 + scc], &ys[buf][r0 * 64]);
        }
    };
    auto compute_tile = [&](int buf) {
        #pragma unroll
        for (int ks = 0; ks < 2; ++ks) {
            const int rc = ((ks * 4 + fkg) ^ fs) * 8;   // swizzled read col
            s8v af[4], bfr[4];
            #pragma unroll
            for (int t = 0; t < 4; ++t)
                af[t]  = *(const s8v*)&xs[buf][(wr * 64 + t * 16 + frow) * 64 + rc];
            #pragma unroll
            for (int t = 0; t < 4; ++t)
                bfr[t] = *(const s8v*)&ys[buf][(wc * 64 + t * 16 + frow) * 64 + rc];
            #pragma unroll
            for (int mr = 0; mr < 4; ++mr)
                #pragma unroll
                for (int nc = 0; nc < 4; ++nc)
                    acc[mr][nc] = __builtin_amdgcn_mfma_f32_16x16x32_bf16(af[mr], bfr[nc], acc[mr][nc], 0, 0, 0);
        }
    };

    if constexpr (DBUF) {
        stage_tile(0, 0);
        int cur = 0;
        for (int t = 0; t < KLEN / 64 - 1; ++t) {
            stage_tile((t + 1) * 64, cur ^ 1);                 // prefetch next tile (stays in flight across barrier)
            asm volatile("s_waitcnt vmcnt(8)" ::: "memory");   // my 8 loads of tile t landed (t+1's 8 may remain)
            __builtin_amdgcn_s_barrier();                      // all waves' tile-t stages landed
            compute_tile(cur);
            asm volatile("s_waitcnt lgkmcnt(0)" ::: "memory"); // my LDS reads complete before signaling
            __builtin_amdgcn_s_barrier();                      // safe to overwrite buf[cur] next iter
            cur ^= 1;
        }
        asm volatile("s_waitcnt vmcnt(0)" ::: "memory");
        __builtin_amdgcn_s_barrier();
        compute_tile(cur);
    } else {
        for (int k0 = 0; k0 < KLEN; k0 += 64) {
            __syncthreads();   // previous iter's LDS reads complete before overwrite
            stage_tile(k0, 0);
            __syncthreads();   // drains vmcnt(0): staged data visible
            compute_tile(0);
        }
    }

    // C/D layout (HW-verified m89): col = lane&15, row = (lane>>4)*4 + reg
    const int lr2 = (lane >> 4) * 4;
    const int lc2 = lane & 15;
    #pragma unroll
    for (int nc = 0; nc < 4; ++nc) {
        int jb = j0 + wc * 64 + nc * 16 + lc2;
        float sb = SCALE ? scB[jb] : 1.0f;
        #pragma unroll
        for (int mr = 0; mr < 4; ++mr) {
            #pragma unroll
            for (int r = 0; r < 4; ++r) {
                int ib = i0 + wr * 64 + mr * 16 + lr2 + r;
                float val = acc[mr][nc][r];
                if (SCALE) val *= scA[ib] * sb;
                if (ATOMIC) unsafeAtomicAdd(&C[(size_t)ib * CSTRIDE + jb], val);
                else        C[(size_t)ib * CSTRIDE + jb] = val;
            }
        }
    }
}

// ---------------------------------------------------------------- bf16 GEMV step: out = sqrt((1/4096) / (Kmat @ vin))
__global__ __launch_bounds__(256) void k_vstep(const unsigned short* __restrict__ Kmat,
                                               const float* __restrict__ vin, float* __restrict__ vout) {
    const int row  = blockIdx.x * 4 + (threadIdx.x >> 6);
    const int lane = threadIdx.x & 63;
    const unsigned short* Krow = Kmat + (size_t)row * NDIM;
    float acc = 0.0f;
    #pragma unroll
    for (int c = 0; c < 8; ++c) {
        int j = (c * 64 + lane) * 8;
        us8 kq = *(const us8*)&Krow[j];
        f4 ua = *(const f4*)&vin[j];
        f4 ub = *(const f4*)&vin[j + 4];
        acc += bf2f(kq[0])*ua[0] + bf2f(kq[1])*ua[1] + bf2f(kq[2])*ua[2] + bf2f(kq[3])*ua[3]
             + bf2f(kq[4])*ub[0] + bf2f(kq[5])*ub[1] + bf2f(kq[6])*ub[2] + bf2f(kq[7])*ub[3];
    }
    #pragma unroll
    for (int off = 32; off; off >>= 1) acc += __shfl_xor(acc, off, 64);
    if (lane == 0) vout[row] = sqrtf((1.0f / 4096.0f) / acc);
}

// ---------------------------------------------------------------- T = A*u_i*exp(A)*v_j in place + TbT = bf16(T^T)
__global__ __launch_bounds__(256) void k_epiT2(float* __restrict__ Am,
                                               const float* __restrict__ u, const float* __restrict__ v,
                                               unsigned short* __restrict__ TbT) {
    __shared__ __align__(16) unsigned short t[64][72];
    const int i0 = blockIdx.y * 64, j0 = blockIdx.x * 64;
    const int r  = threadIdx.x >> 2;
    const int c0 = (threadIdx.x & 3) * 16;
    const float ui = u[i0 + r];
    #pragma unroll
    for (int q = 0; q < 4; ++q) {
        f4 a  = *(const f4*)&Am[(size_t)(i0 + r) * MDIM + j0 + c0 + q * 4];
        f4 vv = *(const f4*)&v[j0 + c0 + q * 4];
        f4 tt;
        #pragma unroll
        for (int e = 0; e < 4; ++e) tt[e] = a[e] * ui * expf(a[e]) * vv[e];
        *(f4*)&Am[(size_t)(i0 + r) * MDIM + j0 + c0 + q * 4] = tt;
        #pragma unroll
        for (int e = 0; e < 4; ++e) t[c0 + q * 4 + e][r] = f2bf(tt[e]);
    }
    __syncthreads();
    const int jj  = threadIdx.x >> 2;
    const int ii0 = (threadIdx.x & 3) * 16;
    #pragma unroll
    for (int h = 0; h < 2; ++h)
        *(us8*)&TbT[(size_t)(j0 + jj) * NDIM + i0 + ii0 + h * 8] = *(const us8*)&t[jj][ii0 + h * 8];
}

// ----------------------------------------------------------------
extern "C" void kernel_launch(void* const* d_in, const int* in_sizes, int n_in,
                              void* d_out, int out_size, void* d_ws, size_t ws_size,
                              hipStream_t stream) {
    const float* x = (const float*)d_in[0];   // [4096,1024]
    const float* y = (const float*)d_in[1];   // [4096,1024]

    float* out_aligned = (float*)d_out;                       // [4096,1024]
    float* Amat        = (float*)d_out + (size_t)MDIM * DDIM; // T region: holds A, then T in place

    // ws phase map (64 MB + 64 KB):
    //   phase 1: [xb 8MB][yb 8MB]                 (dead after cos-GEMM)
    //   phase 2: [Kb 32MB][KbT 32MB]              (Kb overwrites xb/yb)
    //   phase 3: [TbT 32MB over Kb][xbT 8MB over KbT]
    unsigned short* xb  = (unsigned short*)d_ws;
    unsigned short* yb  = xb + (size_t)NDIM * DDIM;
    unsigned short* Kb  = (unsigned short*)d_ws;
    unsigned short* KbT = Kb + (size_t)NDIM * MDIM;
    unsigned short* TbT = Kb;
    unsigned short* xbT = KbT;
    float* u   = (float*)(KbT + (size_t)NDIM * MDIM);
    float* v   = u + NDIM;
    float* inx = v + MDIM;
    float* iny = inx + NDIM;

    k_init_v<<<MDIM / 256, 256, 0, stream>>>(v);
    k_prep<<<(NDIM + MDIM) / 4, 256, 0, stream>>>(x, y, inx, iny, xb, yb);
    k_gemm_nt<DDIM, DDIM, MDIM, 1, 0, 0><<<dim3(MDIM / 128, NDIM / 128), 256, 0, stream>>>(xb, yb, inx, iny, Amat);
    k_exp_both<<<dim3(MDIM / 64, NDIM / 64), 256, 0, stream>>>(Amat, Kb, KbT);   // overwrites xb/yb

    for (int it = 0; it < NITER; ++it) {
        k_vstep<<<NDIM / 4, 256, 0, stream>>>(Kb,  v, u);   // u = sqrt(a / (K  v)), bf16
        k_vstep<<<MDIM / 4, 256, 0, stream>>>(KbT, u, v);   // v = sqrt(b / (K^T u)), bf16
    }

    k_trans_cvt<DDIM, NDIM><<<dim3(DDIM / 64, NDIM / 64), 256, 0, stream>>>(x, xbT);  // over dead KbT
    k_epiT2<<<dim3(MDIM / 64, NDIM / 64), 256, 0, stream>>>(Amat, u, v, TbT);         // over dead Kb

    // final GEMM: split-K=2 (512 blocks = 2/CU) + dbuf pipeline, atomic into zeroed out
    hipMemsetAsync(out_aligned, 0, (size_t)MDIM * DDIM * sizeof(float), stream);
    k_gemm_nt<NDIM, NDIM / 2, DDIM, 0, 1, 1><<<dim3(DDIM / 128, MDIM / 128, 2), 256, 0, stream>>>(
        TbT, xbT, nullptr, nullptr, out_aligned);
}